// Round 6
// baseline (91.468 us; speedup 1.0000x reference)
//
#include <hip/hip_runtime.h>
#include <hip/hip_bf16.h>

#define NB   16384
#define ND   2048
#define NG   8
#define NR   6
#define NKC  48
#define NOUT 54
#define KC2  64
#define NCH2 (ND / KC2)           // 32 chunks
#define NT16 (NB / 16 + NG)       // 1032 tiles of 16 samples
#define LROW 136                  // tier-3 fallback gemm
#define BM   32
#define KC   128
#define NCH  (ND / KC)
#define MAXT (NB / BM + NG)

typedef __attribute__((ext_vector_type(8))) short short8_t;
typedef __attribute__((ext_vector_type(4))) float f32x4;

__device__ __forceinline__ unsigned short f2bf(float x) {
    union { float f; unsigned u; } v; v.f = x;
    unsigned r = v.u + 0x7FFFu + ((v.u >> 16) & 1u);   // RNE
    return (unsigned short)(r >> 16);
}

__device__ __forceinline__ short8_t cvt8(float4 a, float4 b) {
    short8_t s;
    s[0] = (short)f2bf(a.x); s[1] = (short)f2bf(a.y);
    s[2] = (short)f2bf(a.z); s[3] = (short)f2bf(a.w);
    s[4] = (short)f2bf(b.x); s[5] = (short)f2bf(b.y);
    s[6] = (short)f2bf(b.z); s[7] = (short)f2bf(b.w);
    return s;
}

// hardware async global->LDS, 16B/lane; LDS dest wave-uniform base + lane*16
__device__ __forceinline__ void gl_lds16(const void* g, void* s) {
    __builtin_amdgcn_global_load_lds(
        (const __attribute__((address_space(1))) void*)g,
        (__attribute__((address_space(3))) void*)s,
        16, 0, 0);
}

#define WAITV(N) do { asm volatile("s_waitcnt vmcnt(" #N ")" ::: "memory"); \
                      __builtin_amdgcn_sched_barrier(0); } while (0)

// ---- histogram (tier-3) ----
__global__ void hist_kernel(const int* __restrict__ roi, int* __restrict__ counts) {
    int i = blockIdx.x * 256 + threadIdx.x;
    int g = roi[i];
    int lane = threadIdx.x & 63;
    #pragma unroll
    for (int gg = 0; gg < NG; ++gg) {
        unsigned long long m = __ballot(g == gg);
        if (m && lane == (int)(__ffsll((unsigned long long)m) - 1))
            atomicAdd(&counts[gg], (int)__popcll(m));
    }
}

// ---- scatter into packed regions (tier-3) ----
__global__ void scatter_kernel(const int* __restrict__ roi, const int* __restrict__ counts,
                               int* __restrict__ ranks, int* __restrict__ perm) {
    int off[NG];
    int acc = 0;
    #pragma unroll
    for (int gg = 0; gg < NG; ++gg) { off[gg] = acc; acc += counts[gg]; }
    int i = blockIdx.x * 256 + threadIdx.x;
    int g = roi[i];
    int lane = threadIdx.x & 63;
    #pragma unroll
    for (int gg = 0; gg < NG; ++gg) {
        unsigned long long m = __ballot(g == gg);
        if (!m) continue;
        int leader = (int)(__ffsll((unsigned long long)m) - 1);
        int base = 0;
        if (lane == leader) base = atomicAdd(&ranks[gg], (int)__popcll(m));
        base = __shfl(base, leader);
        if (g == gg) {
            int rank = (int)__popcll(m & ((1ull << lane) - 1ull));
            perm[off[gg] + base + rank] = i;
        }
    }
}

// ---- 1-pass scatter into fixed per-group regions of stride NB (tier-1) ----
__global__ void scatter1_kernel(const int* __restrict__ roi, int* __restrict__ cnt,
                                int* __restrict__ perm) {
    int i = blockIdx.x * 256 + threadIdx.x;
    int g = roi[i];
    int lane = threadIdx.x & 63;
    #pragma unroll
    for (int gg = 0; gg < NG; ++gg) {
        unsigned long long m = __ballot(g == gg);
        if (!m) continue;
        int leader = (int)(__ffsll((unsigned long long)m) - 1);
        int base = 0;
        if (lane == leader) base = atomicAdd(&cnt[gg], (int)__popcll(m));
        base = __shfl(base, leader);
        if (g == gg) {
            int rank = (int)__popcll(m & ((1ull << lane) - 1ull));
            perm[gg * NB + base + rank] = i;
        }
    }
}

// ---- W -> bf16 blob, fragment-major, per (g,chunk) 8KB contiguous ----
// unit u (16B): l=u&63, q=(u>>6)&7, c=(u>>9)&31, g=u>>14; n=q>>1, ks=q&1
// content = W[g][n*16+(l&15)][c*64 + ks*32 + (l>>4)*8 .. +8)
__global__ void wconv_kernel(const float* __restrict__ Wreg, const float* __restrict__ Wcls,
                             short* __restrict__ Wbf) {
    int u = blockIdx.x * 256 + threadIdx.x;          // 131072 units
    int l = u & 63;
    int q = (u >> 6) & 7;
    int c = (u >> 9) & 31;
    int g = u >> 14;
    int n = q >> 1, ks = q & 1;
    int row = n * 16 + (l & 15);
    int k   = c * 64 + ks * 32 + (l >> 4) * 8;
    short8_t v = {0, 0, 0, 0, 0, 0, 0, 0};
    if (row < NOUT) {
        const float* s = (row < NR) ? Wreg + (size_t)(g * NR + row) * ND + k
                                    : Wcls + (size_t)(g * NKC + row - NR) * ND + k;
        float4 a = *(const float4*)s;
        float4 b = *(const float4*)(s + 4);
        v = cvt8(a, b);
    }
    *(short8_t*)(Wbf + (size_t)u * 8) = v;
}

// ---- primary: barrier-free per-wave pipelined GEMM, counted vmcnt ----
// One 64-thread block per 16-sample tile. 3-slot private LDS pipeline,
// global_load_lds staging 3 chunks ahead, s_waitcnt vmcnt(24) per chunk.
__launch_bounds__(64, 1)
__global__ void gemm_pipe_kernel(const float* __restrict__ feats,
                                 const short* __restrict__ Wbf,
                                 const float* __restrict__ breg, const float* __restrict__ bcls,
                                 const int* __restrict__ counts, const int* __restrict__ perm,
                                 float* __restrict__ out, int stride) {
    __shared__ __align__(16) char lds[3][12288];   // slot: A 4KB @0, B 8KB @4096

    int l = threadIdx.x;            // 0..63
    int lr = l & 15, lq = l >> 4;
    int t = blockIdx.x;

    int ts[NG + 1]; ts[0] = 0;
    int off[NG]; int acc_ = 0;
    #pragma unroll
    for (int gg = 0; gg < NG; ++gg) {
        int c = counts[gg];
        off[gg] = stride ? gg * stride : acc_;
        acc_ += c;
        ts[gg + 1] = ts[gg] + (c + 15) / 16;
    }
    if (t >= ts[NG]) return;
    int g = 0;
    #pragma unroll
    for (int gg = 0; gg < NG; ++gg) if (t >= ts[gg + 1]) g = gg + 1;
    int gcnt  = counts[g];
    int goff  = off[g];
    int rbase = (t - ts[g]) * 16;
    int nvalid = gcnt - rbase; if (nvalid > 16) nvalid = 16;

    int r = rbase + lr; if (r >= gcnt) r = gcnt - 1;   // clamp; stores masked later
    int smp = perm[goff + r];
    // A stage src: lane l loads row (l&15), float4 at k = c*64 + ks*32 + lq*8 + h*4
    const float* aRow  = feats + (size_t)smp * ND + lq * 8;
    // B stage src: blob granule q at +q*512 shorts, lane at +l*8 (contiguous 1KB/instr)
    const short* bBase = Wbf + (size_t)g * 131072 + l * 8;

    f32x4 acc[4] = {{0,0,0,0},{0,0,0,0},{0,0,0,0},{0,0,0,0}};

#define STAGE(cc, sl) do {                                                    \
        const float* a_ = aRow + (cc) * KC2;                                  \
        gl_lds16(a_,      &lds[sl][0]);                                       \
        gl_lds16(a_ + 4,  &lds[sl][1024]);                                    \
        gl_lds16(a_ + 32, &lds[sl][2048]);                                    \
        gl_lds16(a_ + 36, &lds[sl][3072]);                                    \
        const short* b_ = bBase + (size_t)(cc) * 4096;                        \
        gl_lds16(b_,        &lds[sl][4096]);                                  \
        gl_lds16(b_ +  512, &lds[sl][5120]);                                  \
        gl_lds16(b_ + 1024, &lds[sl][6144]);                                  \
        gl_lds16(b_ + 1536, &lds[sl][7168]);                                  \
        gl_lds16(b_ + 2048, &lds[sl][8192]);                                  \
        gl_lds16(b_ + 2560, &lds[sl][9216]);                                  \
        gl_lds16(b_ + 3072, &lds[sl][10240]);                                 \
        gl_lds16(b_ + 3584, &lds[sl][11264]);                                 \
    } while (0)

    STAGE(0, 0); STAGE(1, 1); STAGE(2, 2);

    #pragma unroll
    for (int c = 0; c < NCH2; ++c) {
        const int sl = c % 3;
        if (c <= NCH2 - 3)      { WAITV(24); }   // chunk c landed; c+1,c+2 in flight
        else if (c == NCH2 - 2) { WAITV(12); }
        else                    { WAITV(0);  }
        #pragma unroll
        for (int ks = 0; ks < 2; ++ks) {
            float4 a0 = *(const float4*)&lds[sl][ks * 2048 + l * 16];
            float4 a1 = *(const float4*)&lds[sl][ks * 2048 + 1024 + l * 16];
            short8_t af = cvt8(a0, a1);
            #pragma unroll
            for (int n = 0; n < 4; ++n) {
                short8_t bf = *(const short8_t*)&lds[sl][4096 + (n * 2 + ks) * 1024 + l * 16];
                acc[n] = __builtin_amdgcn_mfma_f32_16x16x32_bf16(af, bf, acc[n], 0, 0, 0);
            }
        }
        if (c + 3 < NCH2) STAGE(c + 3, sl);      // reuse slot after consume (WAR-safe)
    }
#undef STAGE

    const int B6 = NB * NR;
    #pragma unroll
    for (int n = 0; n < 4; ++n) {
        f32x4 v = acc[n];
        int col = n * 16 + lr;
        if (col < NOUT) {
            #pragma unroll
            for (int j = 0; j < 4; ++j) {
                int row = lq * 4 + j;
                if (row < nvalid) {
                    int s2 = perm[goff + rbase + row];
                    if (col < NR) out[s2 * NR + col] = v[j] + breg[g * NR + col];
                    else          out[B6 + s2 * NKC + (col - NR)] = v[j] + bcls[g * NKC + (col - NR)];
                }
            }
        }
    }
}

// ---- tier-3 GEMM (proven R3 path, no blob needed) ----
__launch_bounds__(256, 3)
__global__ void gemm_kernel(const float* __restrict__ feats,
                            const float* __restrict__ Wreg, const float* __restrict__ breg,
                            const float* __restrict__ Wcls, const float* __restrict__ bcls,
                            const int* __restrict__ counts, const int* __restrict__ perm,
                            float* __restrict__ out, int stride) {
    __shared__ __align__(16) short Bsh[2][64][LROW];
    __shared__ int sRow[BM];

    int ts[NG + 1]; ts[0] = 0;
    int off[NG]; int acc = 0;
    #pragma unroll
    for (int gg = 0; gg < NG; ++gg) {
        int c = counts[gg];
        off[gg] = stride ? gg * stride : acc;
        acc += c;
        ts[gg + 1] = ts[gg] + (c + BM - 1) / BM;
    }
    int b = blockIdx.x;
    if (b >= ts[NG]) return;
    int g = 0;
    #pragma unroll
    for (int gg = 0; gg < NG; ++gg) if (b >= ts[gg + 1]) g = gg + 1;
    int gcnt  = counts[g];
    int goff  = off[g];
    int rbase = (b - ts[g]) * BM;
    int nvalid = gcnt - rbase; if (nvalid > BM) nvalid = BM;

    int tid = threadIdx.x;
    if (tid < BM) {
        int r = rbase + tid;
        if (r >= gcnt) r = gcnt - 1;
        sRow[tid] = perm[goff + r];
    }
    __syncthreads();

    int rB = tid >> 2;
    int cq = tid & 3;
    const float* wsrc = nullptr;
    if (rB < NR)        wsrc = Wreg + ((size_t)g * NR + rB) * ND + cq * 32;
    else if (rB < NOUT) wsrc = Wcls + ((size_t)g * NKC + (rB - NR)) * ND + cq * 32;

    int w = tid >> 6, l = tid & 63, lr = l & 15, lq = l >> 4;
    int mt = w & 1, nh = w >> 1;
    const float* aptr = feats + (size_t)sRow[mt * 16 + lr] * ND + lq * 8;
    const short* brp = (const short*)&Bsh[0][0][0] + (nh * 32 + lr) * LROW + lq * 8;

    f32x4 acc0 = {0, 0, 0, 0}, acc1 = {0, 0, 0, 0};
    float4 rb[8];

    if (wsrc) {
        #pragma unroll
        for (int i = 0; i < 8; ++i) rb[i] = *(const float4*)(wsrc + 4 * i);
    } else {
        #pragma unroll
        for (int i = 0; i < 8; ++i) rb[i] = make_float4(0.f, 0.f, 0.f, 0.f);
    }
    {
        short* bw = &Bsh[0][rB][cq * 32];
        #pragma unroll
        for (int j = 0; j < 4; ++j) *(short8_t*)(bw + 8 * j) = cvt8(rb[2 * j], rb[2 * j + 1]);
    }
    __syncthreads();

    #pragma unroll
    for (int c = 0; c < NCH; ++c) {
        const int cur = c & 1, nxt = cur ^ 1;
        if (c + 1 < NCH && wsrc) {
            const float* s = wsrc + (c + 1) * KC;
            #pragma unroll
            for (int i = 0; i < 8; ++i) rb[i] = *(const float4*)(s + 4 * i);
        }
        const short* bp = brp + cur * (64 * LROW);
        const float* ap = aptr + c * KC;
        #pragma unroll
        for (int ks = 0; ks < 4; ++ks) {
            float4 a0 = *(const float4*)(ap + ks * 32);
            float4 a1 = *(const float4*)(ap + ks * 32 + 4);
            short8_t af = cvt8(a0, a1);
            short8_t b0 = *(const short8_t*)(bp + ks * 32);
            short8_t b1 = *(const short8_t*)(bp + 16 * LROW + ks * 32);
            acc0 = __builtin_amdgcn_mfma_f32_16x16x32_bf16(af, b0, acc0, 0, 0, 0);
            acc1 = __builtin_amdgcn_mfma_f32_16x16x32_bf16(af, b1, acc1, 0, 0, 0);
        }
        if (c + 1 < NCH && wsrc) {
            short* bw = &Bsh[nxt][rB][cq * 32];
            #pragma unroll
            for (int j = 0; j < 4; ++j) *(short8_t*)(bw + 8 * j) = cvt8(rb[2 * j], rb[2 * j + 1]);
        } else if (c + 1 < NCH) {
            short8_t z = {0,0,0,0,0,0,0,0};
            short* bw = &Bsh[nxt][rB][cq * 32];
            #pragma unroll
            for (int j = 0; j < 4; ++j) *(short8_t*)(bw + 8 * j) = z;
        }
        __syncthreads();
    }

    const int B6 = NB * NR;
    #pragma unroll
    for (int n = 0; n < 2; ++n) {
        f32x4 v = n ? acc1 : acc0;
        int col = nh * 32 + n * 16 + lr;
        if (col < NOUT) {
            #pragma unroll
            for (int j = 0; j < 4; ++j) {
                int row = mt * 16 + lq * 4 + j;
                if (row < nvalid) {
                    int smp = sRow[row];
                    if (col < NR) out[smp * NR + col] = v[j] + breg[g * NR + col];
                    else          out[B6 + smp * NKC + (col - NR)] = v[j] + bcls[g * NKC + (col - NR)];
                }
            }
        }
    }
}

// ---- tier-4: exact fp32, one wave per sample ----
__global__ void fallback_kernel(const float* __restrict__ feats, const int* __restrict__ roi,
                                const float* __restrict__ Wreg, const float* __restrict__ breg,
                                const float* __restrict__ Wcls, const float* __restrict__ bcls,
                                float* __restrict__ out) {
    int i = blockIdx.x;
    int lane = threadIdx.x;
    int g = roi[i];
    const float* frow = feats + (size_t)i * ND;
    float f[32];
    #pragma unroll
    for (int q = 0; q < 32; ++q) f[q] = frow[lane + 64 * q];
    for (int o = 0; o < NOUT; ++o) {
        const float* wrow = (o < NR) ? Wreg + ((size_t)g * NR + o) * ND
                                     : Wcls + ((size_t)g * NKC + (o - NR)) * ND;
        float p = 0.f;
        #pragma unroll
        for (int q = 0; q < 32; ++q) p += f[q] * wrow[lane + 64 * q];
        #pragma unroll
        for (int s = 32; s; s >>= 1) p += __shfl_xor(p, s);
        if (lane == 0) {
            if (o < NR) out[i * NR + o] = p + breg[g * NR + o];
            else        out[NB * NR + i * NKC + (o - NR)] = p + bcls[g * NKC + (o - NR)];
        }
    }
}

extern "C" void kernel_launch(void* const* d_in, const int* in_sizes, int n_in,
                              void* d_out, int out_size, void* d_ws, size_t ws_size,
                              hipStream_t stream) {
    const float* feats = (const float*)d_in[0];
    const int*   roi   = (const int*)d_in[1];
    const float* Wreg  = (const float*)d_in[2];
    const float* breg  = (const float*)d_in[3];
    const float* Wcls  = (const float*)d_in[4];
    const float* bcls  = (const float*)d_in[5];
    float* out = (float*)d_out;

    const size_t wbfBytes = (size_t)NG * 131072 * 2;              // 2 MB blob
    const size_t need_t1 = wbfBytes + 256 + (size_t)NG * NB * 4;  // blob + 1-pass perm
    const size_t need_t3 = 256 + (size_t)NB * 4;                  // packed-perm path

    if (ws_size >= need_t1) {
        short* Wbf = (short*)d_ws;
        int* cnt  = (int*)((char*)d_ws + wbfBytes);
        int* perm = cnt + 64;
        hipMemsetAsync(cnt, 0, 8 * sizeof(int), stream);
        wconv_kernel<<<512, 256, 0, stream>>>(Wreg, Wcls, Wbf);
        scatter1_kernel<<<NB / 256, 256, 0, stream>>>(roi, cnt, perm);
        gemm_pipe_kernel<<<NT16, 64, 0, stream>>>(feats, Wbf, breg, bcls, cnt, perm, out, NB);
    } else if (ws_size >= need_t3) {
        int* counts = (int*)d_ws;
        int* ranks  = counts + 8;
        int* perm   = counts + 64;
        hipMemsetAsync(counts, 0, 16 * sizeof(int), stream);
        hist_kernel<<<NB / 256, 256, 0, stream>>>(roi, counts);
        scatter_kernel<<<NB / 256, 256, 0, stream>>>(roi, counts, ranks, perm);
        gemm_kernel<<<MAXT, 256, 0, stream>>>(feats, Wreg, breg, Wcls, bcls, counts, perm, out, 0);
    } else {
        fallback_kernel<<<NB, 64, 0, stream>>>(feats, roi, Wreg, breg, Wcls, bcls, out);
    }
}

// Round 7
// 73.528 us; speedup vs baseline: 1.2440x; 1.2440x over previous
//
#include <hip/hip_runtime.h>
#include <hip/hip_bf16.h>

#define NB   16384
#define ND   2048
#define NG   8
#define NR   6
#define NKC  48
#define NOUT 54
#define KW   512                  // K per wave (4 waves split ND)
#define KC2  64
#define NCW  (KW / KC2)           // 8 chunks per wave
#define NT16 (NB / 16 + NG)       // 1032 tiles of 16 samples
#define LROW 136                  // tier-3 fallback gemm
#define BM   32
#define KC   128
#define NCH  (ND / KC)
#define MAXT (NB / BM + NG)

typedef __attribute__((ext_vector_type(8))) short short8_t;
typedef __attribute__((ext_vector_type(4))) float f32x4;

__device__ __forceinline__ unsigned short f2bf(float x) {
    union { float f; unsigned u; } v; v.f = x;
    unsigned r = v.u + 0x7FFFu + ((v.u >> 16) & 1u);   // RNE
    return (unsigned short)(r >> 16);
}

__device__ __forceinline__ short8_t cvt8(float4 a, float4 b) {
    short8_t s;
    s[0] = (short)f2bf(a.x); s[1] = (short)f2bf(a.y);
    s[2] = (short)f2bf(a.z); s[3] = (short)f2bf(a.w);
    s[4] = (short)f2bf(b.x); s[5] = (short)f2bf(b.y);
    s[6] = (short)f2bf(b.z); s[7] = (short)f2bf(b.w);
    return s;
}

// ---- histogram (tier-3) ----
__global__ void hist_kernel(const int* __restrict__ roi, int* __restrict__ counts) {
    int i = blockIdx.x * 256 + threadIdx.x;
    int g = roi[i];
    int lane = threadIdx.x & 63;
    #pragma unroll
    for (int gg = 0; gg < NG; ++gg) {
        unsigned long long m = __ballot(g == gg);
        if (m && lane == (int)(__ffsll((unsigned long long)m) - 1))
            atomicAdd(&counts[gg], (int)__popcll(m));
    }
}

// ---- scatter into packed regions (tier-3) ----
__global__ void scatter_kernel(const int* __restrict__ roi, const int* __restrict__ counts,
                               int* __restrict__ ranks, int* __restrict__ perm) {
    int off[NG];
    int acc = 0;
    #pragma unroll
    for (int gg = 0; gg < NG; ++gg) { off[gg] = acc; acc += counts[gg]; }
    int i = blockIdx.x * 256 + threadIdx.x;
    int g = roi[i];
    int lane = threadIdx.x & 63;
    #pragma unroll
    for (int gg = 0; gg < NG; ++gg) {
        unsigned long long m = __ballot(g == gg);
        if (!m) continue;
        int leader = (int)(__ffsll((unsigned long long)m) - 1);
        int base = 0;
        if (lane == leader) base = atomicAdd(&ranks[gg], (int)__popcll(m));
        base = __shfl(base, leader);
        if (g == gg) {
            int rank = (int)__popcll(m & ((1ull << lane) - 1ull));
            perm[off[gg] + base + rank] = i;
        }
    }
}

// ---- 1-pass scatter into fixed per-group regions of stride NB (tier-1) ----
__global__ void scatter1_kernel(const int* __restrict__ roi, int* __restrict__ cnt,
                                int* __restrict__ perm) {
    int i = blockIdx.x * 256 + threadIdx.x;
    int g = roi[i];
    int lane = threadIdx.x & 63;
    #pragma unroll
    for (int gg = 0; gg < NG; ++gg) {
        unsigned long long m = __ballot(g == gg);
        if (!m) continue;
        int leader = (int)(__ffsll((unsigned long long)m) - 1);
        int base = 0;
        if (lane == leader) base = atomicAdd(&cnt[gg], (int)__popcll(m));
        base = __shfl(base, leader);
        if (g == gg) {
            int rank = (int)__popcll(m & ((1ull << lane) - 1ull));
            perm[gg * NB + base + rank] = i;
        }
    }
}

// ---- W -> bf16 blob, fragment-major, per (g,chunk) 8KB contiguous ----
// unit u (16B): l=u&63, q=(u>>6)&7, c=(u>>9)&31, g=u>>14; n=q>>1, ks=q&1
// content = W[g][n*16+(l&15)][c*64 + ks*32 + (l>>4)*8 .. +8)
__global__ void wconv_kernel(const float* __restrict__ Wreg, const float* __restrict__ Wcls,
                             short* __restrict__ Wbf) {
    int u = blockIdx.x * 256 + threadIdx.x;          // 131072 units
    int l = u & 63;
    int q = (u >> 6) & 7;
    int c = (u >> 9) & 31;
    int g = u >> 14;
    int n = q >> 1, ks = q & 1;
    int row = n * 16 + (l & 15);
    int k   = c * 64 + ks * 32 + (l >> 4) * 8;
    short8_t v = {0, 0, 0, 0, 0, 0, 0, 0};
    if (row < NOUT) {
        const float* s = (row < NR) ? Wreg + (size_t)(g * NR + row) * ND + k
                                    : Wcls + (size_t)(g * NKC + row - NR) * ND + k;
        float4 a = *(const float4*)s;
        float4 b = *(const float4*)(s + 4);
        v = cvt8(a, b);
    }
    *(short8_t*)(Wbf + (size_t)u * 8) = v;
}

// ---- primary: K-split GEMM. 1 block = 16 samples; wave w does K [512w,512w+512).
// A: global->reg->cvt (per-lane fragment loads). B: fragment-major blob (L2).
// LDS reduce of the 4 partial accumulators, wave 0 writes bias+scatter. ----
__launch_bounds__(256, 4)
__global__ void gemm_ks_kernel(const float* __restrict__ feats,
                               const short* __restrict__ Wbf,
                               const float* __restrict__ breg, const float* __restrict__ bcls,
                               const int* __restrict__ counts, const int* __restrict__ perm,
                               float* __restrict__ out, int stride) {
    __shared__ float sacc[3][16][66];   // +2 pad: 2-way max on 32 banks

    int tid = threadIdx.x, w = tid >> 6, l = tid & 63, lr = l & 15, lq = l >> 4;
    int t = blockIdx.x;

    int ts[NG + 1]; ts[0] = 0;
    int off[NG]; int acc_ = 0;
    #pragma unroll
    for (int gg = 0; gg < NG; ++gg) {
        int c = counts[gg];
        off[gg] = stride ? gg * stride : acc_;
        acc_ += c;
        ts[gg + 1] = ts[gg] + (c + 15) / 16;
    }
    if (t >= ts[NG]) return;
    int g = 0;
    #pragma unroll
    for (int gg = 0; gg < NG; ++gg) if (t >= ts[gg + 1]) g = gg + 1;
    int gcnt  = counts[g];
    int goff  = off[g];
    int rbase = (t - ts[g]) * 16;
    int nvalid = gcnt - rbase; if (nvalid > 16) nvalid = 16;

    int r = rbase + lr; if (r >= gcnt) r = gcnt - 1;   // clamp; stores masked later
    int smp = perm[goff + r];
    const float* aRow  = feats + (size_t)smp * ND + w * KW + lq * 8;
    const short* bBase = Wbf + (size_t)g * 131072 + (size_t)w * NCW * 4096 + l * 8;

    f32x4 acc[4] = {{0,0,0,0},{0,0,0,0},{0,0,0,0},{0,0,0,0}};

    #pragma unroll
    for (int c = 0; c < NCW; ++c) {
        const float* ap = aRow + c * KC2;
        float4 a0 = *(const float4*)(ap);
        float4 a1 = *(const float4*)(ap + 4);
        float4 a2 = *(const float4*)(ap + 32);
        float4 a3 = *(const float4*)(ap + 36);
        const short* bp = bBase + (size_t)c * 4096;
        short8_t b0 = *(const short8_t*)(bp);
        short8_t b1 = *(const short8_t*)(bp + 512);
        short8_t b2 = *(const short8_t*)(bp + 1024);
        short8_t b3 = *(const short8_t*)(bp + 1536);
        short8_t b4 = *(const short8_t*)(bp + 2048);
        short8_t b5 = *(const short8_t*)(bp + 2560);
        short8_t b6 = *(const short8_t*)(bp + 3072);
        short8_t b7 = *(const short8_t*)(bp + 3584);
        short8_t af0 = cvt8(a0, a1);
        short8_t af1 = cvt8(a2, a3);
        acc[0] = __builtin_amdgcn_mfma_f32_16x16x32_bf16(af0, b0, acc[0], 0, 0, 0);
        acc[1] = __builtin_amdgcn_mfma_f32_16x16x32_bf16(af0, b2, acc[1], 0, 0, 0);
        acc[2] = __builtin_amdgcn_mfma_f32_16x16x32_bf16(af0, b4, acc[2], 0, 0, 0);
        acc[3] = __builtin_amdgcn_mfma_f32_16x16x32_bf16(af0, b6, acc[3], 0, 0, 0);
        acc[0] = __builtin_amdgcn_mfma_f32_16x16x32_bf16(af1, b1, acc[0], 0, 0, 0);
        acc[1] = __builtin_amdgcn_mfma_f32_16x16x32_bf16(af1, b3, acc[1], 0, 0, 0);
        acc[2] = __builtin_amdgcn_mfma_f32_16x16x32_bf16(af1, b5, acc[2], 0, 0, 0);
        acc[3] = __builtin_amdgcn_mfma_f32_16x16x32_bf16(af1, b7, acc[3], 0, 0, 0);
    }

    // waves 1..3 park partials in LDS
    if (w > 0) {
        #pragma unroll
        for (int n = 0; n < 4; ++n)
            #pragma unroll
            for (int j = 0; j < 4; ++j)
                sacc[w - 1][lq * 4 + j][n * 16 + lr] = acc[n][j];
    }
    __syncthreads();

    if (w == 0) {
        const int B6 = NB * NR;
        #pragma unroll
        for (int n = 0; n < 4; ++n) {
            int col = n * 16 + lr;
            if (col < NOUT) {
                #pragma unroll
                for (int j = 0; j < 4; ++j) {
                    int row = lq * 4 + j;
                    if (row < nvalid) {
                        float v = acc[n][j]
                                + sacc[0][row][col] + sacc[1][row][col] + sacc[2][row][col];
                        int s2 = perm[goff + rbase + row];
                        if (col < NR) out[s2 * NR + col] = v + breg[g * NR + col];
                        else          out[B6 + s2 * NKC + (col - NR)] = v + bcls[g * NKC + (col - NR)];
                    }
                }
            }
        }
    }
}

// ---- tier-3 GEMM (proven R3 path, no blob needed) ----
__launch_bounds__(256, 3)
__global__ void gemm_kernel(const float* __restrict__ feats,
                            const float* __restrict__ Wreg, const float* __restrict__ breg,
                            const float* __restrict__ Wcls, const float* __restrict__ bcls,
                            const int* __restrict__ counts, const int* __restrict__ perm,
                            float* __restrict__ out, int stride) {
    __shared__ __align__(16) short Bsh[2][64][LROW];
    __shared__ int sRow[BM];

    int ts[NG + 1]; ts[0] = 0;
    int off[NG]; int acc = 0;
    #pragma unroll
    for (int gg = 0; gg < NG; ++gg) {
        int c = counts[gg];
        off[gg] = stride ? gg * stride : acc;
        acc += c;
        ts[gg + 1] = ts[gg] + (c + BM - 1) / BM;
    }
    int b = blockIdx.x;
    if (b >= ts[NG]) return;
    int g = 0;
    #pragma unroll
    for (int gg = 0; gg < NG; ++gg) if (b >= ts[gg + 1]) g = gg + 1;
    int gcnt  = counts[g];
    int goff  = off[g];
    int rbase = (b - ts[g]) * BM;
    int nvalid = gcnt - rbase; if (nvalid > BM) nvalid = BM;

    int tid = threadIdx.x;
    if (tid < BM) {
        int r = rbase + tid;
        if (r >= gcnt) r = gcnt - 1;
        sRow[tid] = perm[goff + r];
    }
    __syncthreads();

    int rB = tid >> 2;
    int cq = tid & 3;
    const float* wsrc = nullptr;
    if (rB < NR)        wsrc = Wreg + ((size_t)g * NR + rB) * ND + cq * 32;
    else if (rB < NOUT) wsrc = Wcls + ((size_t)g * NKC + (rB - NR)) * ND + cq * 32;

    int w = tid >> 6, l = tid & 63, lr = l & 15, lq = l >> 4;
    int mt = w & 1, nh = w >> 1;
    const float* aptr = feats + (size_t)sRow[mt * 16 + lr] * ND + lq * 8;
    const short* brp = (const short*)&Bsh[0][0][0] + (nh * 32 + lr) * LROW + lq * 8;

    f32x4 acc0 = {0, 0, 0, 0}, acc1 = {0, 0, 0, 0};
    float4 rb[8];

    if (wsrc) {
        #pragma unroll
        for (int i = 0; i < 8; ++i) rb[i] = *(const float4*)(wsrc + 4 * i);
    } else {
        #pragma unroll
        for (int i = 0; i < 8; ++i) rb[i] = make_float4(0.f, 0.f, 0.f, 0.f);
    }
    {
        short* bw = &Bsh[0][rB][cq * 32];
        #pragma unroll
        for (int j = 0; j < 4; ++j) *(short8_t*)(bw + 8 * j) = cvt8(rb[2 * j], rb[2 * j + 1]);
    }
    __syncthreads();

    #pragma unroll
    for (int c = 0; c < NCH; ++c) {
        const int cur = c & 1, nxt = cur ^ 1;
        if (c + 1 < NCH && wsrc) {
            const float* s = wsrc + (c + 1) * KC;
            #pragma unroll
            for (int i = 0; i < 8; ++i) rb[i] = *(const float4*)(s + 4 * i);
        }
        const short* bp = brp + cur * (64 * LROW);
        const float* ap = aptr + c * KC;
        #pragma unroll
        for (int ks = 0; ks < 4; ++ks) {
            float4 a0 = *(const float4*)(ap + ks * 32);
            float4 a1 = *(const float4*)(ap + ks * 32 + 4);
            short8_t af = cvt8(a0, a1);
            short8_t b0 = *(const short8_t*)(bp + ks * 32);
            short8_t b1 = *(const short8_t*)(bp + 16 * LROW + ks * 32);
            acc0 = __builtin_amdgcn_mfma_f32_16x16x32_bf16(af, b0, acc0, 0, 0, 0);
            acc1 = __builtin_amdgcn_mfma_f32_16x16x32_bf16(af, b1, acc1, 0, 0, 0);
        }
        if (c + 1 < NCH && wsrc) {
            short* bw = &Bsh[nxt][rB][cq * 32];
            #pragma unroll
            for (int j = 0; j < 4; ++j) *(short8_t*)(bw + 8 * j) = cvt8(rb[2 * j], rb[2 * j + 1]);
        } else if (c + 1 < NCH) {
            short8_t z = {0,0,0,0,0,0,0,0};
            short* bw = &Bsh[nxt][rB][cq * 32];
            #pragma unroll
            for (int j = 0; j < 4; ++j) *(short8_t*)(bw + 8 * j) = z;
        }
        __syncthreads();
    }

    const int B6 = NB * NR;
    #pragma unroll
    for (int n = 0; n < 2; ++n) {
        f32x4 v = n ? acc1 : acc0;
        int col = nh * 32 + n * 16 + lr;
        if (col < NOUT) {
            #pragma unroll
            for (int j = 0; j < 4; ++j) {
                int row = mt * 16 + lq * 4 + j;
                if (row < nvalid) {
                    int smp = sRow[row];
                    if (col < NR) out[smp * NR + col] = v[j] + breg[g * NR + col];
                    else          out[B6 + smp * NKC + (col - NR)] = v[j] + bcls[g * NKC + (col - NR)];
                }
            }
        }
    }
}

// ---- tier-4: exact fp32, one wave per sample ----
__global__ void fallback_kernel(const float* __restrict__ feats, const int* __restrict__ roi,
                                const float* __restrict__ Wreg, const float* __restrict__ breg,
                                const float* __restrict__ Wcls, const float* __restrict__ bcls,
                                float* __restrict__ out) {
    int i = blockIdx.x;
    int lane = threadIdx.x;
    int g = roi[i];
    const float* frow = feats + (size_t)i * ND;
    float f[32];
    #pragma unroll
    for (int q = 0; q < 32; ++q) f[q] = frow[lane + 64 * q];
    for (int o = 0; o < NOUT; ++o) {
        const float* wrow = (o < NR) ? Wreg + ((size_t)g * NR + o) * ND
                                     : Wcls + ((size_t)g * NKC + (o - NR)) * ND;
        float p = 0.f;
        #pragma unroll
        for (int q = 0; q < 32; ++q) p += f[q] * wrow[lane + 64 * q];
        #pragma unroll
        for (int s = 32; s; s >>= 1) p += __shfl_xor(p, s);
        if (lane == 0) {
            if (o < NR) out[i * NR + o] = p + breg[g * NR + o];
            else        out[NB * NR + i * NKC + (o - NR)] = p + bcls[g * NKC + (o - NR)];
        }
    }
}

extern "C" void kernel_launch(void* const* d_in, const int* in_sizes, int n_in,
                              void* d_out, int out_size, void* d_ws, size_t ws_size,
                              hipStream_t stream) {
    const float* feats = (const float*)d_in[0];
    const int*   roi   = (const int*)d_in[1];
    const float* Wreg  = (const float*)d_in[2];
    const float* breg  = (const float*)d_in[3];
    const float* Wcls  = (const float*)d_in[4];
    const float* bcls  = (const float*)d_in[5];
    float* out = (float*)d_out;

    const size_t wbfBytes = (size_t)NG * 131072 * 2;              // 2 MB blob
    const size_t need_t1 = wbfBytes + 256 + (size_t)NG * NB * 4;  // blob + 1-pass perm
    const size_t need_t3 = 256 + (size_t)NB * 4;                  // packed-perm path

    if (ws_size >= need_t1) {
        short* Wbf = (short*)d_ws;
        int* cnt  = (int*)((char*)d_ws + wbfBytes);
        int* perm = cnt + 64;
        hipMemsetAsync(cnt, 0, 8 * sizeof(int), stream);
        wconv_kernel<<<512, 256, 0, stream>>>(Wreg, Wcls, Wbf);
        scatter1_kernel<<<NB / 256, 256, 0, stream>>>(roi, cnt, perm);
        gemm_ks_kernel<<<NT16, 256, 0, stream>>>(feats, Wbf, breg, bcls, cnt, perm, out, NB);
    } else if (ws_size >= need_t3) {
        int* counts = (int*)d_ws;
        int* ranks  = counts + 8;
        int* perm   = counts + 64;
        hipMemsetAsync(counts, 0, 16 * sizeof(int), stream);
        hist_kernel<<<NB / 256, 256, 0, stream>>>(roi, counts);
        scatter_kernel<<<NB / 256, 256, 0, stream>>>(roi, counts, ranks, perm);
        gemm_kernel<<<MAXT, 256, 0, stream>>>(feats, Wreg, breg, Wcls, bcls, counts, perm, out, 0);
    } else {
        fallback_kernel<<<NB, 64, 0, stream>>>(feats, roi, Wreg, breg, Wcls, bcls, out);
    }
}

// Round 8
// 69.911 us; speedup vs baseline: 1.3083x; 1.0517x over previous
//
#include <hip/hip_runtime.h>
#include <hip/hip_bf16.h>

#define NB   16384
#define ND   2048
#define NG   8
#define NR   6
#define NKC  48
#define NOUT 54
#define BM   32
#define KC3  64
#define NCH3 (ND / KC3)           // 32 chunks
#define SLOT 16384                // LDS slot: A 8KB + B 8KB
#define LROW 136                  // tier-3 fallback gemm
#define KC   128
#define NCH  (ND / KC)
#define MAXT (NB / BM + NG)       // 520 tiles max

typedef __attribute__((ext_vector_type(8))) short short8_t;
typedef __attribute__((ext_vector_type(4))) float f32x4;

__device__ __forceinline__ unsigned short f2bf(float x) {
    union { float f; unsigned u; } v; v.f = x;
    unsigned r = v.u + 0x7FFFu + ((v.u >> 16) & 1u);   // RNE
    return (unsigned short)(r >> 16);
}

__device__ __forceinline__ short8_t cvt8(float4 a, float4 b) {
    short8_t s;
    s[0] = (short)f2bf(a.x); s[1] = (short)f2bf(a.y);
    s[2] = (short)f2bf(a.z); s[3] = (short)f2bf(a.w);
    s[4] = (short)f2bf(b.x); s[5] = (short)f2bf(b.y);
    s[6] = (short)f2bf(b.z); s[7] = (short)f2bf(b.w);
    return s;
}

// hardware async global->LDS, 16B/lane; LDS dest wave-uniform base + lane*16
__device__ __forceinline__ void gl_lds16(const void* g, void* s) {
    __builtin_amdgcn_global_load_lds(
        (const __attribute__((address_space(1))) void*)g,
        (__attribute__((address_space(3))) void*)s,
        16, 0, 0);
}

#define WAITV(N) do { asm volatile("s_waitcnt vmcnt(" #N ")" ::: "memory"); \
                      __builtin_amdgcn_sched_barrier(0); } while (0)
#define BARRIER() do { __builtin_amdgcn_s_barrier(); \
                       __builtin_amdgcn_sched_barrier(0); } while (0)

// ---- histogram (tier-3) ----
__global__ void hist_kernel(const int* __restrict__ roi, int* __restrict__ counts) {
    int i = blockIdx.x * 256 + threadIdx.x;
    int g = roi[i];
    int lane = threadIdx.x & 63;
    #pragma unroll
    for (int gg = 0; gg < NG; ++gg) {
        unsigned long long m = __ballot(g == gg);
        if (m && lane == (int)(__ffsll((unsigned long long)m) - 1))
            atomicAdd(&counts[gg], (int)__popcll(m));
    }
}

// ---- scatter into packed regions (tier-3) ----
__global__ void scatter_kernel(const int* __restrict__ roi, const int* __restrict__ counts,
                               int* __restrict__ ranks, int* __restrict__ perm) {
    int off[NG];
    int acc = 0;
    #pragma unroll
    for (int gg = 0; gg < NG; ++gg) { off[gg] = acc; acc += counts[gg]; }
    int i = blockIdx.x * 256 + threadIdx.x;
    int g = roi[i];
    int lane = threadIdx.x & 63;
    #pragma unroll
    for (int gg = 0; gg < NG; ++gg) {
        unsigned long long m = __ballot(g == gg);
        if (!m) continue;
        int leader = (int)(__ffsll((unsigned long long)m) - 1);
        int base = 0;
        if (lane == leader) base = atomicAdd(&ranks[gg], (int)__popcll(m));
        base = __shfl(base, leader);
        if (g == gg) {
            int rank = (int)__popcll(m & ((1ull << lane) - 1ull));
            perm[off[gg] + base + rank] = i;
        }
    }
}

// ---- 1-pass scatter into fixed per-group regions of stride NB (tier-1) ----
__global__ void scatter1_kernel(const int* __restrict__ roi, int* __restrict__ cnt,
                                int* __restrict__ perm) {
    int i = blockIdx.x * 256 + threadIdx.x;
    int g = roi[i];
    int lane = threadIdx.x & 63;
    #pragma unroll
    for (int gg = 0; gg < NG; ++gg) {
        unsigned long long m = __ballot(g == gg);
        if (!m) continue;
        int leader = (int)(__ffsll((unsigned long long)m) - 1);
        int base = 0;
        if (lane == leader) base = atomicAdd(&cnt[gg], (int)__popcll(m));
        base = __shfl(base, leader);
        if (g == gg) {
            int rank = (int)__popcll(m & ((1ull << lane) - 1ull));
            perm[gg * NB + base + rank] = i;
        }
    }
}

// ---- W -> bf16 blob, fragment-major per (g, chunk, nh, n, ks), 1KB granules ----
// unit u (16B): l=u&63, ks=(u>>6)&1, n=(u>>7)&1, nh=(u>>8)&1, c=(u>>9)&31, g=u>>14
// content = W[g][nh*32 + n*16 + (l&15)][c*64 + ks*32 + (l>>4)*8 .. +8)
__global__ void wconv_kernel(const float* __restrict__ Wreg, const float* __restrict__ Wcls,
                             short* __restrict__ Wbf) {
    int u = blockIdx.x * 256 + threadIdx.x;          // 131072 units
    int l  = u & 63;
    int ks = (u >> 6) & 1;
    int n  = (u >> 7) & 1;
    int nh = (u >> 8) & 1;
    int c  = (u >> 9) & 31;
    int g  = u >> 14;
    int row = nh * 32 + n * 16 + (l & 15);
    int k   = c * 64 + ks * 32 + (l >> 4) * 8;
    short8_t v = {0, 0, 0, 0, 0, 0, 0, 0};
    if (row < NOUT) {
        const float* s = (row < NR) ? Wreg + (size_t)(g * NR + row) * ND + k
                                    : Wcls + (size_t)(g * NKC + row - NR) * ND + k;
        float4 a = *(const float4*)s;
        float4 b = *(const float4*)(s + 4);
        v = cvt8(a, b);
    }
    *(short8_t*)(Wbf + (size_t)u * 8) = v;
}

// ---- primary: counted-vmcnt pipelined grouped GEMM (T3+T4 discipline) ----
// 520 blocks x 4 waves. Ring-3 LDS slots; wave w stages its own A granules
// (mt=w&1, ks=w>>1, h=0/1) and B granules (nh=w>>1, n=w&1, ks=0/1).
// Loop: STAGE(c+2) ; vmcnt(8) ; barrier ; ds_read+MFMA ; barrier.  Never vmcnt(0).
__launch_bounds__(256, 2)
__global__ void gemm_p3_kernel(const float* __restrict__ feats,
                               const short* __restrict__ Wbf,
                               const float* __restrict__ breg, const float* __restrict__ bcls,
                               const int* __restrict__ counts, const int* __restrict__ perm,
                               float* __restrict__ out, int stride) {
    __shared__ __align__(16) char lds[3][SLOT];   // slot: A 8KB @0 | B 8KB @8192
    __shared__ int sRow[BM];

    int ts[NG + 1]; ts[0] = 0;
    int off[NG]; int acc_ = 0;
    #pragma unroll
    for (int gg = 0; gg < NG; ++gg) {
        int c = counts[gg];
        off[gg] = stride ? gg * stride : acc_;
        acc_ += c;
        ts[gg + 1] = ts[gg] + (c + BM - 1) / BM;
    }
    int b = blockIdx.x;
    if (b >= ts[NG]) return;
    int g = 0;
    #pragma unroll
    for (int gg = 0; gg < NG; ++gg) if (b >= ts[gg + 1]) g = gg + 1;
    int gcnt  = counts[g];
    int goff  = off[g];
    int rbase = (b - ts[g]) * BM;
    int nvalid = gcnt - rbase; if (nvalid > BM) nvalid = BM;

    int tid = threadIdx.x;
    if (tid < BM) {
        int r = rbase + tid;
        if (r >= gcnt) r = gcnt - 1;   // clamp; stores masked by nvalid
        sRow[tid] = perm[goff + r];
    }
    __syncthreads();   // preamble only; also drains preamble vmcnt to 0

    int w = tid >> 6, l = tid & 63, lr = l & 15, lq = l >> 4;
    int mt = w & 1, nh = w >> 1;

    // ---- staging sources/dests for THIS wave ----
    // A granule (mt=w&1, ksA=w>>1, h): lane l -> feats[sRow[mt*16+lr]][c*64 + ksA*32 + lq*8 + h*4]
    const float* paBase = feats + (size_t)sRow[mt * 16 + lr] * ND + nh * 32 + lq * 8;
    char* ldsA = &lds[0][0] + (mt * 4096 + nh * 2048);            // +h*1024, slot offset added later
    // B granule (nhB=w>>1, nB=w&1, ks): blob byte off ((g*32+c)*8 + (nhB*2+nB)*2 + ks)*1024
    const short* pbBase = Wbf + ((size_t)g * 32 * 8 + (nh * 2 + mt) * 2) * 512 + l * 8;
    char* ldsB = &lds[0][8192] + (nh * 4096 + mt * 2048);         // +ks*1024

#define STAGE(cc, sl) do {                                                     \
        const float* a_ = paBase + (size_t)(cc) * KC3;                         \
        gl_lds16(a_,     ldsA + (sl) * SLOT);                                  \
        gl_lds16(a_ + 4, ldsA + (sl) * SLOT + 1024);                           \
        const short* b_ = pbBase + (size_t)(cc) * 4096;                        \
        gl_lds16(b_,       ldsB + (sl) * SLOT);                                \
        gl_lds16(b_ + 512, ldsB + (sl) * SLOT + 1024);                         \
    } while (0)

    f32x4 acc0 = {0, 0, 0, 0}, acc1 = {0, 0, 0, 0};

    STAGE(0, 0); STAGE(1, 1);      // 8 outstanding per wave

    #pragma unroll
    for (int c = 0; c < NCH3; ++c) {
        const int sl = c % 3;
        if (c + 2 < NCH3) STAGE(c + 2, (c + 2) % 3);   // 12 outstanding
        if (c < NCH3 - 2)       WAITV(8);              // chunk c landed; 2 in flight
        else if (c == NCH3 - 2) WAITV(4);
        else                    WAITV(0);
        BARRIER();                                     // all waves' chunk-c parts visible
        {
            const char* sa = &lds[sl][mt * 4096];
            const char* sb = &lds[sl][8192 + nh * 4096];
            #pragma unroll
            for (int ks = 0; ks < 2; ++ks) {
                float4 a0 = *(const float4*)(sa + ks * 2048 + l * 16);
                float4 a1 = *(const float4*)(sa + ks * 2048 + 1024 + l * 16);
                short8_t af = cvt8(a0, a1);
                short8_t b0 = *(const short8_t*)(sb + ks * 1024 + l * 16);
                short8_t b1 = *(const short8_t*)(sb + 2048 + ks * 1024 + l * 16);
                acc0 = __builtin_amdgcn_mfma_f32_16x16x32_bf16(af, b0, acc0, 0, 0, 0);
                acc1 = __builtin_amdgcn_mfma_f32_16x16x32_bf16(af, b1, acc1, 0, 0, 0);
            }
        }
        BARRIER();                                     // slot c%3 free for reuse
    }
#undef STAGE

    // ---- epilogue: bias + scatter to routed rows ----
    const int B6 = NB * NR;
    #pragma unroll
    for (int n = 0; n < 2; ++n) {
        f32x4 v = n ? acc1 : acc0;
        int col = nh * 32 + n * 16 + lr;
        if (col < NOUT) {
            #pragma unroll
            for (int j = 0; j < 4; ++j) {
                int row = mt * 16 + lq * 4 + j;
                if (row < nvalid) {
                    int smp = sRow[row];
                    if (col < NR) out[smp * NR + col] = v[j] + breg[g * NR + col];
                    else          out[B6 + smp * NKC + (col - NR)] = v[j] + bcls[g * NKC + (col - NR)];
                }
            }
        }
    }
}

// ---- tier-3 GEMM (proven R3 path, no blob needed) ----
__launch_bounds__(256, 3)
__global__ void gemm_kernel(const float* __restrict__ feats,
                            const float* __restrict__ Wreg, const float* __restrict__ breg,
                            const float* __restrict__ Wcls, const float* __restrict__ bcls,
                            const int* __restrict__ counts, const int* __restrict__ perm,
                            float* __restrict__ out, int stride) {
    __shared__ __align__(16) short Bsh[2][64][LROW];
    __shared__ int sRow[BM];

    int ts[NG + 1]; ts[0] = 0;
    int off[NG]; int acc = 0;
    #pragma unroll
    for (int gg = 0; gg < NG; ++gg) {
        int c = counts[gg];
        off[gg] = stride ? gg * stride : acc;
        acc += c;
        ts[gg + 1] = ts[gg] + (c + BM - 1) / BM;
    }
    int b = blockIdx.x;
    if (b >= ts[NG]) return;
    int g = 0;
    #pragma unroll
    for (int gg = 0; gg < NG; ++gg) if (b >= ts[gg + 1]) g = gg + 1;
    int gcnt  = counts[g];
    int goff  = off[g];
    int rbase = (b - ts[g]) * BM;
    int nvalid = gcnt - rbase; if (nvalid > BM) nvalid = BM;

    int tid = threadIdx.x;
    if (tid < BM) {
        int r = rbase + tid;
        if (r >= gcnt) r = gcnt - 1;
        sRow[tid] = perm[goff + r];
    }
    __syncthreads();

    int rB = tid >> 2;
    int cq = tid & 3;
    const float* wsrc = nullptr;
    if (rB < NR)        wsrc = Wreg + ((size_t)g * NR + rB) * ND + cq * 32;
    else if (rB < NOUT) wsrc = Wcls + ((size_t)g * NKC + (rB - NR)) * ND + cq * 32;

    int w = tid >> 6, l = tid & 63, lr = l & 15, lq = l >> 4;
    int mt = w & 1, nh = w >> 1;
    const float* aptr = feats + (size_t)sRow[mt * 16 + lr] * ND + lq * 8;
    const short* brp = (const short*)&Bsh[0][0][0] + (nh * 32 + lr) * LROW + lq * 8;

    f32x4 acc0 = {0, 0, 0, 0}, acc1 = {0, 0, 0, 0};
    float4 rb[8];

    if (wsrc) {
        #pragma unroll
        for (int i = 0; i < 8; ++i) rb[i] = *(const float4*)(wsrc + 4 * i);
    } else {
        #pragma unroll
        for (int i = 0; i < 8; ++i) rb[i] = make_float4(0.f, 0.f, 0.f, 0.f);
    }
    {
        short* bw = &Bsh[0][rB][cq * 32];
        #pragma unroll
        for (int j = 0; j < 4; ++j) *(short8_t*)(bw + 8 * j) = cvt8(rb[2 * j], rb[2 * j + 1]);
    }
    __syncthreads();

    #pragma unroll
    for (int c = 0; c < NCH; ++c) {
        const int cur = c & 1, nxt = cur ^ 1;
        if (c + 1 < NCH && wsrc) {
            const float* s = wsrc + (c + 1) * KC;
            #pragma unroll
            for (int i = 0; i < 8; ++i) rb[i] = *(const float4*)(s + 4 * i);
        }
        const short* bp = brp + cur * (64 * LROW);
        const float* ap = aptr + c * KC;
        #pragma unroll
        for (int ks = 0; ks < 4; ++ks) {
            float4 a0 = *(const float4*)(ap + ks * 32);
            float4 a1 = *(const float4*)(ap + ks * 32 + 4);
            short8_t af = cvt8(a0, a1);
            short8_t b0 = *(const short8_t*)(bp + ks * 32);
            short8_t b1 = *(const short8_t*)(bp + 16 * LROW + ks * 32);
            acc0 = __builtin_amdgcn_mfma_f32_16x16x32_bf16(af, b0, acc0, 0, 0, 0);
            acc1 = __builtin_amdgcn_mfma_f32_16x16x32_bf16(af, b1, acc1, 0, 0, 0);
        }
        if (c + 1 < NCH && wsrc) {
            short* bw = &Bsh[nxt][rB][cq * 32];
            #pragma unroll
            for (int j = 0; j < 4; ++j) *(short8_t*)(bw + 8 * j) = cvt8(rb[2 * j], rb[2 * j + 1]);
        } else if (c + 1 < NCH) {
            short8_t z = {0,0,0,0,0,0,0,0};
            short* bw = &Bsh[nxt][rB][cq * 32];
            #pragma unroll
            for (int j = 0; j < 4; ++j) *(short8_t*)(bw + 8 * j) = z;
        }
        __syncthreads();
    }

    const int B6 = NB * NR;
    #pragma unroll
    for (int n = 0; n < 2; ++n) {
        f32x4 v = n ? acc1 : acc0;
        int col = nh * 32 + n * 16 + lr;
        if (col < NOUT) {
            #pragma unroll
            for (int j = 0; j < 4; ++j) {
                int row = mt * 16 + lq * 4 + j;
                if (row < nvalid) {
                    int smp = sRow[row];
                    if (col < NR) out[smp * NR + col] = v[j] + breg[g * NR + col];
                    else          out[B6 + smp * NKC + (col - NR)] = v[j] + bcls[g * NKC + (col - NR)];
                }
            }
        }
    }
}

// ---- tier-4: exact fp32, one wave per sample ----
__global__ void fallback_kernel(const float* __restrict__ feats, const int* __restrict__ roi,
                                const float* __restrict__ Wreg, const float* __restrict__ breg,
                                const float* __restrict__ Wcls, const float* __restrict__ bcls,
                                float* __restrict__ out) {
    int i = blockIdx.x;
    int lane = threadIdx.x;
    int g = roi[i];
    const float* frow = feats + (size_t)i * ND;
    float f[32];
    #pragma unroll
    for (int q = 0; q < 32; ++q) f[q] = frow[lane + 64 * q];
    for (int o = 0; o < NOUT; ++o) {
        const float* wrow = (o < NR) ? Wreg + ((size_t)g * NR + o) * ND
                                     : Wcls + ((size_t)g * NKC + (o - NR)) * ND;
        float p = 0.f;
        #pragma unroll
        for (int q = 0; q < 32; ++q) p += f[q] * wrow[lane + 64 * q];
        #pragma unroll
        for (int s = 32; s; s >>= 1) p += __shfl_xor(p, s);
        if (lane == 0) {
            if (o < NR) out[i * NR + o] = p + breg[g * NR + o];
            else        out[NB * NR + i * NKC + (o - NR)] = p + bcls[g * NKC + (o - NR)];
        }
    }
}

extern "C" void kernel_launch(void* const* d_in, const int* in_sizes, int n_in,
                              void* d_out, int out_size, void* d_ws, size_t ws_size,
                              hipStream_t stream) {
    const float* feats = (const float*)d_in[0];
    const int*   roi   = (const int*)d_in[1];
    const float* Wreg  = (const float*)d_in[2];
    const float* breg  = (const float*)d_in[3];
    const float* Wcls  = (const float*)d_in[4];
    const float* bcls  = (const float*)d_in[5];
    float* out = (float*)d_out;

    const size_t wbfBytes = (size_t)NG * 131072 * 2;              // 2 MB blob
    const size_t need_t1 = wbfBytes + 256 + (size_t)NG * NB * 4;  // blob + 1-pass perm
    const size_t need_t3 = 256 + (size_t)NB * 4;                  // packed-perm path

    if (ws_size >= need_t1) {
        short* Wbf = (short*)d_ws;
        int* cnt  = (int*)((char*)d_ws + wbfBytes);
        int* perm = cnt + 64;
        hipMemsetAsync(cnt, 0, 8 * sizeof(int), stream);
        wconv_kernel<<<512, 256, 0, stream>>>(Wreg, Wcls, Wbf);
        scatter1_kernel<<<NB / 256, 256, 0, stream>>>(roi, cnt, perm);
        gemm_p3_kernel<<<MAXT, 256, 0, stream>>>(feats, Wbf, breg, bcls, cnt, perm, out, NB);
    } else if (ws_size >= need_t3) {
        int* counts = (int*)d_ws;
        int* ranks  = counts + 8;
        int* perm   = counts + 64;
        hipMemsetAsync(counts, 0, 16 * sizeof(int), stream);
        hist_kernel<<<NB / 256, 256, 0, stream>>>(roi, counts);
        scatter_kernel<<<NB / 256, 256, 0, stream>>>(roi, counts, ranks, perm);
        gemm_kernel<<<MAXT, 256, 0, stream>>>(feats, Wreg, breg, Wcls, bcls, counts, perm, out, 0);
    } else {
        fallback_kernel<<<NB, 64, 0, stream>>>(feats, roi, Wreg, breg, Wcls, bcls, out);
    }
}